// Round 12
// baseline (260.955 us; speedup 1.0000x reference)
//
#include <hip/hip_runtime.h>
#include <hip/hip_bf16.h>
#include <hip/hip_fp16.h>

#define NN 2048
#define KK 8
#define DD 32
#define ZSZ (KK * NN * DD)   // 524288 floats
#define ZS2 (KK * NN * 16)   // 262144 u32 per partial chunk (fp16x2-packed)
#define PSTR 20              // P row stride (u32)
#define NCH 32               // m-chunks; grid = 32 x 32 = 1024 blocks -> 4 blocks/CU

typedef __attribute__((ext_vector_type(8))) short short8;
typedef __attribute__((ext_vector_type(4))) float f32x4;
typedef __attribute__((ext_vector_type(4))) unsigned int u32x4;

union UU { u32x4 q; short8 v; unsigned int u[4]; };

#define SELHI 0x07060302u
#define SELLO 0x05040100u

__device__ __forceinline__ unsigned int prm(unsigned int a, unsigned int b, unsigned int sel) {
  return __builtin_amdgcn_perm(a, b, sel);
}
__device__ __forceinline__ unsigned int bfr(float x) {
  unsigned int u = __float_as_uint(x);
  return (u + 0x7fffu + ((u >> 16) & 1u)) >> 16;
}
__device__ __forceinline__ unsigned int packp(float a, float b) {  // bf16: a->lo, b->hi
  union { __hip_bfloat162 h; unsigned int u; } cv;
  cv.h = __float22bfloat162_rn(make_float2(a, b));
  return cv.u;
}
__device__ __forceinline__ unsigned int packh(float a, float b) {  // fp16: a->lo, b->hi
  union { __half2 h; unsigned int u; } cv;
  cv.h = __float22half2_rn(make_float2(a, b));
  return cv.u;
}
__device__ __forceinline__ float2 unpackh(unsigned int u) {
  union { unsigned int u; __half2 h; } cv;
  cv.u = u;
  return __half22float2(cv.h);
}
__device__ __forceinline__ f32x4 MF(short8 a, short8 b, f32x4 c) {
  return __builtin_amdgcn_mfma_f32_16x16x32_bf16(a, b, c, 0, 0, 0);
}
__device__ __forceinline__ short8 as_s8(u32x4 x) { UU u; u.q = x; return u.v; }

// ------- merged: proj+l2norm+pack (blocks 0..256) + adj bitmask (blocks 256..4352) ----
__global__ __launch_bounds__(256) void pm_kernel(const float* __restrict__ feat,
                                                 const float* __restrict__ W,
                                                 const float* __restrict__ bias,
                                                 float* __restrict__ Z,
                                                 unsigned short* __restrict__ Zghi,
                                                 unsigned short* __restrict__ Zthi,
                                                 const int* __restrict__ adj,
                                                 unsigned int* __restrict__ mbits) {
  const int t = threadIdx.x;
  if (blockIdx.x < 256) {
    const int nb = blockIdx.x * 8;
    const int k = t >> 5, c = t & 31;
    float s[8];
#pragma unroll
    for (int j = 0; j < 8; ++j) s[j] = bias[k * DD + c];
    const float* w = W + (k * 128) * DD + c;
    const float* fp = feat + nb * 128;  // uniform across block -> s_load
#pragma unroll 4
    for (int d = 0; d < 128; ++d) {
      float wv = w[d * DD];
#pragma unroll
      for (int j = 0; j < 8; ++j) s[j] = fmaf(fp[j * 128 + d], wv, s[j]);
    }
    unsigned int hi[8];
#pragma unroll
    for (int j = 0; j < 8; ++j) {
      float sq = s[j] * s[j];
#pragma unroll
      for (int off = 16; off > 0; off >>= 1) sq += __shfl_xor(sq, off, 32);
      float z = s[j] / fmaxf(sqrtf(sq), 1e-12f);
      Z[(k * NN + nb + j) * DD + c] = z;
      hi[j] = bfr(z);
      Zghi[(k * NN + nb + j) * DD + c] = (unsigned short)hi[j];
    }
    uint4 tp = make_uint4(hi[0] | (hi[1] << 16), hi[2] | (hi[3] << 16),
                          hi[4] | (hi[5] << 16), hi[6] | (hi[7] << 16));
    *(uint4*)&Zthi[(size_t)k * DD * NN + (size_t)c * NN + nb] = tp;
  } else {
    const int base = (blockIdx.x - 256) * 1024 + t;
    const int lane = t & 63;
    int v[4];
#pragma unroll
    for (int rr = 0; rr < 4; ++rr) v[rr] = adj[base + 256 * rr];
#pragma unroll
    for (int rr = 0; rr < 4; ++rr) {
      int idx = base + 256 * rr;
      unsigned long long b = __ballot(v[rr] > 0);
      if (lane == 0) mbits[idx >> 5] = (unsigned int)b;
      if (lane == 32) mbits[idx >> 5] = (unsigned int)(b >> 32);
    }
  }
}

// ------- fused: Z = l2norm(Zin + sum fp16 partials); write Z fp32 + hi + hi^T -------
template <int NCt>
__global__ __launch_bounds__(256) void rp_kernel(const float* __restrict__ Zin,
                                                 const unsigned int* __restrict__ partU,
                                                 float* __restrict__ Zout,
                                                 unsigned short* __restrict__ Zghi,
                                                 unsigned short* __restrict__ Zthi) {
  __shared__ unsigned short T[DD][33];
  const int t = threadIdx.x;
  const int k = blockIdx.x >> 6, mt = blockIdx.x & 63;
  const int m0 = mt * 32;
  const int mloc = t >> 3, c4 = t & 7;
  const size_t idx = (size_t)(k * NN + m0 + mloc) * DD + 4 * c4;
  float4 v = *(const float4*)&Zin[idx];
#pragma unroll
  for (int j = 0; j < NCt; ++j) {
    uint2 pp = *(const uint2*)&partU[(size_t)j * ZS2 + (size_t)(k * NN + m0 + mloc) * 16 + 2 * c4];
    float2 f0 = unpackh(pp.x), f1 = unpackh(pp.y);
    v.x += f0.x; v.y += f0.y; v.z += f1.x; v.w += f1.y;
  }
  float sq = v.x * v.x + v.y * v.y + v.z * v.z + v.w * v.w;
  sq += __shfl_xor(sq, 1, 8);
  sq += __shfl_xor(sq, 2, 8);
  sq += __shfl_xor(sq, 4, 8);
  const float sc = 1.0f / fmaxf(sqrtf(sq), 1e-12f);
  float z[4] = {v.x * sc, v.y * sc, v.z * sc, v.w * sc};
  *(float4*)&Zout[idx] = make_float4(z[0], z[1], z[2], z[3]);
  unsigned int hi[4];
#pragma unroll
  for (int e = 0; e < 4; ++e) {
    hi[e] = bfr(z[e]);
    T[4 * c4 + e][mloc] = (unsigned short)hi[e];
  }
  *(uint2*)&Zghi[idx] = make_uint2(hi[0] | (hi[1] << 16), hi[2] | (hi[3] << 16));
  __syncthreads();
  const int cloc = t >> 3, m4 = t & 7;
  unsigned int o0 = (unsigned int)T[cloc][4 * m4 + 0] | ((unsigned int)T[cloc][4 * m4 + 1] << 16);
  unsigned int o1 = (unsigned int)T[cloc][4 * m4 + 2] | ((unsigned int)T[cloc][4 * m4 + 3] << 16);
  *(uint2*)&Zthi[(size_t)k * DD * NN + (size_t)cloc * NN + m0 + 4 * m4] = make_uint2(o0, o1);
}

// ---------------- fused MFMA iteration: gram + softmax(k) + aggregate ----------------
// grid (32 n-blocks, NCH chunks) = 1024 blocks, 4 blocks/CU (37 KB LDS, <=128 VGPR).
// P: one per-wave 320-u32 region, reused serially per k-pair (same-wave DS ordering
// makes the WAR safe); packed softmax results held in 32 VGPRs meanwhile.
template <int NS>
__global__ __launch_bounds__(256, 4) void iter_kernel(const unsigned short* __restrict__ Zghi,
                                                      const unsigned short* __restrict__ Zthi,
                                                      const unsigned int* __restrict__ mbits,
                                                      unsigned int* __restrict__ partU) {
  __shared__ __align__(16) unsigned int lds[8192 + 4 * 16 * PSTR];  // 37888 B
  const int t = threadIdx.x;
  const int w = t >> 6;
  const int lane = t & 63;
  const int l15 = lane & 15;
  const int g = lane >> 4;
  const int nw = blockIdx.x * 64 + w * 16;
  const int mchunk = blockIdx.y * (NS * 32);

  const unsigned int* Zg = (const unsigned int*)Zghi;
  const unsigned int* Zt = (const unsigned int*)Zthi;

  short8 A[KK];
#pragma unroll
  for (int k = 0; k < KK; ++k)
    A[k] = as_s8(*(const u32x4*)&Zg[(size_t)(k * NN + nw + l15) * 16 + 4 * g]);

  // preload this chunk's mask words (NS words of 32 m per n-row)
  unsigned int mwa[4][NS];
#pragma unroll
  for (int r = 0; r < 4; ++r)
#pragma unroll
    for (int wi = 0; wi < NS; ++wi)
      mwa[r][wi] = mbits[(size_t)(nw + 4 * g + r) * 64 + (mchunk >> 5) + wi];

  f32x4 O[KK][2];
#pragma unroll
  for (int k = 0; k < KK; ++k)
#pragma unroll
    for (int ch = 0; ch < 2; ++ch) O[k][ch] = {0.0f, 0.0f, 0.0f, 0.0f};

  const int sqd = t & 3;
  const int sr0 = t >> 2;

  u32x4 Lgh[4], Lth[4];
  auto do_loads = [&](int mb) {
#pragma unroll
    for (int j = 0; j < 4; ++j) {
      int r = 64 * j + sr0;
      int k = r >> 5, rm = r & 31;
      Lgh[j] = *(const u32x4*)&Zg[(size_t)k * (NN * 16) + (size_t)(mb + rm) * 16 + sqd * 4];
      Lth[j] = *(const u32x4*)&Zt[(size_t)k * (NN * 16) + (size_t)rm * (NN / 2) + (mb >> 1) + sqd * 4];
    }
  };
  do_loads(mchunk);

  unsigned int* Pw = &lds[8192 + w * (16 * PSTR)];

#pragma unroll
  for (int st = 0; st < NS; ++st) {
    const int mb = mchunk + st * 32;
    __syncthreads();
#pragma unroll
    for (int j = 0; j < 4; ++j) {
      int r = 64 * j + sr0;
      *(u32x4*)&lds[r * 16 + 4 * sqd] = Lgh[j];
      *(u32x4*)&lds[4096 + r * 16 + 4 * sqd] = Lth[j];
    }
    __syncthreads();
    if (st + 1 < NS) do_loads(mb + 32);

    // ---- gram + softmax per sub; pack P into registers (4kp x 2sub x 4r u32) ----
    unsigned int pp[4][2][4];
#pragma unroll
    for (int sub = 0; sub < 2; ++sub) {
      f32x4 S[KK];
#pragma unroll
      for (int k = 0; k < KK; ++k) {
        int m = 16 * sub + l15;
        u32x4 bh = *(const u32x4*)&lds[(k * 32 + m) * 16 + 4 * g];
        f32x4 z = {0.0f, 0.0f, 0.0f, 0.0f};
        S[k] = MF(A[k], as_s8(bh), z);
      }
#pragma unroll
      for (int r = 0; r < 4; ++r) {
        float e[KK];
        float sum = 0.0f;
#pragma unroll
        for (int k = 0; k < KK; ++k) { e[k] = __expf(S[k][r]); sum += e[k]; }
        int ml = 16 * sub + l15;
        float f = ((mwa[r][st] >> ml) & 1u) ? __builtin_amdgcn_rcpf(sum) : 0.0f;
#pragma unroll
        for (int k = 0; k < KK; ++k) S[k][r] = e[k] * f;
#pragma unroll
        for (int kp = 0; kp < 4; ++kp)
          pp[kp][sub][r] = packp(S[2 * kp][r], S[2 * kp + 1][r]);
      }
    }

    // ---- per k-pair: P write -> read-back (C->A transpose) -> aggregate ----
#pragma unroll
    for (int kp = 0; kp < 4; ++kp) {
#pragma unroll
      for (int sub = 0; sub < 2; ++sub)
#pragma unroll
        for (int r = 0; r < 4; ++r)
          Pw[(4 * g + r) * PSTR + 16 * sub + l15] = pp[kp][sub][r];

      const unsigned int* Pr = &Pw[l15 * PSTR + 8 * g];
      u32x4 a0 = *(const u32x4*)Pr;
      u32x4 a1 = *(const u32x4*)(Pr + 4);
      UU pk0, pk1;
      pk0.u[0] = prm(a0.y, a0.x, SELLO); pk0.u[1] = prm(a0.w, a0.z, SELLO);
      pk0.u[2] = prm(a1.y, a1.x, SELLO); pk0.u[3] = prm(a1.w, a1.z, SELLO);
      pk1.u[0] = prm(a0.y, a0.x, SELHI); pk1.u[1] = prm(a0.w, a0.z, SELHI);
      pk1.u[2] = prm(a1.y, a1.x, SELHI); pk1.u[3] = prm(a1.w, a1.z, SELHI);
#pragma unroll
      for (int kk = 0; kk < 2; ++kk) {
        int k = 2 * kp + kk;
#pragma unroll
        for (int ch = 0; ch < 2; ++ch) {
          int c = 16 * ch + l15;
          u32x4 b = *(const u32x4*)&lds[4096 + (k * 32 + c) * 16 + 4 * g];
          O[k][ch] = MF(kk ? pk1.v : pk0.v, as_s8(b), O[k][ch]);
        }
      }
    }
  }

  // ---- write partials fp16-packed: partU[chunk][k][n][c2] ----
  unsigned int* dst = partU + (size_t)blockIdx.y * ZS2;
  const int even = ((l15 & 1) == 0);
#pragma unroll
  for (int k = 0; k < KK; ++k)
#pragma unroll
    for (int ch = 0; ch < 2; ++ch) {
      f32x4 o = O[k][ch];
#pragma unroll
      for (int r = 0; r < 4; ++r) {
        float partner = __shfl_xor(o[r], 1);
        if (even) {
          dst[(size_t)(k * NN + nw + 4 * g + r) * 16 + ((16 * ch + l15) >> 1)] =
              packh(o[r], partner);
        }
      }
    }
}

// ---------------- final: residual + reduce + l2norm + [N][K*D] output ----------------
template <int NCt>
__global__ __launch_bounds__(256) void ro_kernel(const float* __restrict__ Zin,
                                                 const unsigned int* __restrict__ partU,
                                                 float* __restrict__ out) {
  const int n = blockIdx.x, t = threadIdx.x;
  const int k = t >> 5, c = t & 31;
  float v = Zin[(size_t)(k * NN + n) * DD + c];
#pragma unroll
  for (int j = 0; j < NCt; ++j) {
    unsigned int pu = partU[(size_t)j * ZS2 + (size_t)(k * NN + n) * 16 + (c >> 1)];
    float2 f = unpackh(pu);
    v += (c & 1) ? f.y : f.x;
  }
  float sq = v * v;
#pragma unroll
  for (int off = 16; off > 0; off >>= 1) sq += __shfl_xor(sq, off, 32);
  out[n * (KK * DD) + t] = v / fmaxf(sqrtf(sq), 1e-12f);
}

extern "C" void kernel_launch(void* const* d_in, const int* in_sizes, int n_in,
                              void* d_out, int out_size, void* d_ws, size_t ws_size,
                              hipStream_t stream) {
  const int* adj = (const int*)d_in[0];
  const float* feat = (const float*)d_in[1];
  const float* W = (const float*)d_in[2];
  const float* b = (const float*)d_in[3];
  float* out = (float*)d_out;

  float* Z0 = (float*)d_ws;
  float* Z1 = Z0 + ZSZ;
  unsigned short* Zghi = (unsigned short*)(Z1 + ZSZ);
  unsigned short* Zthi = Zghi + ZSZ;
  unsigned int* mbits = (unsigned int*)(Zthi + ZSZ);
  unsigned int* partU = mbits + NN * 64;  // NCH * 1 MB = 32 MB

  pm_kernel<<<256 + 4096, 256, 0, stream>>>(feat, W, b, Z0, Zghi, Zthi, adj, mbits);

  float* zi = Z0;
  float* zo = Z1;
  for (int it = 0; it < 4; ++it) {
    iter_kernel<2><<<dim3(32, NCH), 256, 0, stream>>>(Zghi, Zthi, mbits, partU);
    if (it < 3) {
      rp_kernel<NCH><<<512, 256, 0, stream>>>(zi, partU, zo, Zghi, Zthi);
      float* tmp = zi; zi = zo; zo = tmp;
    } else {
      ro_kernel<NCH><<<NN, 256, 0, stream>>>(zi, partU, out);
    }
  }
}

// Round 13
// 201.002 us; speedup vs baseline: 1.2983x; 1.2983x over previous
//
#include <hip/hip_runtime.h>
#include <hip/hip_bf16.h>
#include <hip/hip_fp16.h>

#define NN 2048
#define KK 8
#define DD 32
#define ZSZ (KK * NN * DD)   // 524288 floats
#define ZS2 (KK * NN * 16)   // 262144 u32 per partial chunk (fp16x2-packed)
#define PSTR 20              // P row stride (u32)
#define NCH 16               // m-chunks; grid = 32 x 16 = 512 blocks -> 2 blocks/CU

typedef __attribute__((ext_vector_type(8))) short short8;
typedef __attribute__((ext_vector_type(4))) float f32x4;
typedef __attribute__((ext_vector_type(4))) unsigned int u32x4;

union UU { u32x4 q; short8 v; unsigned int u[4]; };

#define SELHI 0x07060302u
#define SELLO 0x05040100u

__device__ __forceinline__ unsigned int prm(unsigned int a, unsigned int b, unsigned int sel) {
  return __builtin_amdgcn_perm(a, b, sel);
}
__device__ __forceinline__ unsigned int bfr(float x) {
  unsigned int u = __float_as_uint(x);
  return (u + 0x7fffu + ((u >> 16) & 1u)) >> 16;
}
__device__ __forceinline__ unsigned int packp(float a, float b) {  // bf16: a->lo, b->hi
  union { __hip_bfloat162 h; unsigned int u; } cv;
  cv.h = __float22bfloat162_rn(make_float2(a, b));
  return cv.u;
}
__device__ __forceinline__ unsigned int packh(float a, float b) {  // fp16: a->lo, b->hi
  union { __half2 h; unsigned int u; } cv;
  cv.h = __float22half2_rn(make_float2(a, b));
  return cv.u;
}
__device__ __forceinline__ float2 unpackh(unsigned int u) {
  union { unsigned int u; __half2 h; } cv;
  cv.u = u;
  return __half22float2(cv.h);
}
__device__ __forceinline__ f32x4 MF(short8 a, short8 b, f32x4 c) {
  return __builtin_amdgcn_mfma_f32_16x16x32_bf16(a, b, c, 0, 0, 0);
}
__device__ __forceinline__ short8 as_s8(u32x4 x) { UU u; u.q = x; return u.v; }

// ------- merged: proj+l2norm+pack (blocks 0..256) + adj bitmask (blocks 256..4352) ----
__global__ __launch_bounds__(256) void pm_kernel(const float* __restrict__ feat,
                                                 const float* __restrict__ W,
                                                 const float* __restrict__ bias,
                                                 float* __restrict__ Z,
                                                 unsigned short* __restrict__ Zghi,
                                                 unsigned short* __restrict__ Zthi,
                                                 const int* __restrict__ adj,
                                                 unsigned int* __restrict__ mbits) {
  const int t = threadIdx.x;
  if (blockIdx.x < 256) {
    const int nb = blockIdx.x * 8;
    const int k = t >> 5, c = t & 31;
    float s[8];
#pragma unroll
    for (int j = 0; j < 8; ++j) s[j] = bias[k * DD + c];
    const float* w = W + (k * 128) * DD + c;
    const float* fp = feat + nb * 128;  // uniform across block -> s_load
#pragma unroll 4
    for (int d = 0; d < 128; ++d) {
      float wv = w[d * DD];
#pragma unroll
      for (int j = 0; j < 8; ++j) s[j] = fmaf(fp[j * 128 + d], wv, s[j]);
    }
    unsigned int hi[8];
#pragma unroll
    for (int j = 0; j < 8; ++j) {
      float sq = s[j] * s[j];
#pragma unroll
      for (int off = 16; off > 0; off >>= 1) sq += __shfl_xor(sq, off, 32);
      float z = s[j] / fmaxf(sqrtf(sq), 1e-12f);
      Z[(k * NN + nb + j) * DD + c] = z;
      hi[j] = bfr(z);
      Zghi[(k * NN + nb + j) * DD + c] = (unsigned short)hi[j];
    }
    uint4 tp = make_uint4(hi[0] | (hi[1] << 16), hi[2] | (hi[3] << 16),
                          hi[4] | (hi[5] << 16), hi[6] | (hi[7] << 16));
    *(uint4*)&Zthi[(size_t)k * DD * NN + (size_t)c * NN + nb] = tp;
  } else {
    const int base = (blockIdx.x - 256) * 1024 + t;
    const int lane = t & 63;
    int v[4];
#pragma unroll
    for (int rr = 0; rr < 4; ++rr) v[rr] = adj[base + 256 * rr];
#pragma unroll
    for (int rr = 0; rr < 4; ++rr) {
      int idx = base + 256 * rr;
      unsigned long long b = __ballot(v[rr] > 0);
      if (lane == 0) mbits[idx >> 5] = (unsigned int)b;
      if (lane == 32) mbits[idx >> 5] = (unsigned int)(b >> 32);
    }
  }
}

// ------- fused: Z = l2norm(Zin + sum fp16 partials); write Z fp32 + hi + hi^T -------
template <int NCt>
__global__ __launch_bounds__(256) void rp_kernel(const float* __restrict__ Zin,
                                                 const unsigned int* __restrict__ partU,
                                                 float* __restrict__ Zout,
                                                 unsigned short* __restrict__ Zghi,
                                                 unsigned short* __restrict__ Zthi) {
  __shared__ unsigned short T[DD][33];
  const int t = threadIdx.x;
  const int k = blockIdx.x >> 6, mt = blockIdx.x & 63;
  const int m0 = mt * 32;
  const int mloc = t >> 3, c4 = t & 7;
  const size_t idx = (size_t)(k * NN + m0 + mloc) * DD + 4 * c4;
  float4 v = *(const float4*)&Zin[idx];
#pragma unroll
  for (int j = 0; j < NCt; ++j) {
    uint2 pp = *(const uint2*)&partU[(size_t)j * ZS2 + (size_t)(k * NN + m0 + mloc) * 16 + 2 * c4];
    float2 f0 = unpackh(pp.x), f1 = unpackh(pp.y);
    v.x += f0.x; v.y += f0.y; v.z += f1.x; v.w += f1.y;
  }
  float sq = v.x * v.x + v.y * v.y + v.z * v.z + v.w * v.w;
  sq += __shfl_xor(sq, 1, 8);
  sq += __shfl_xor(sq, 2, 8);
  sq += __shfl_xor(sq, 4, 8);
  const float sc = 1.0f / fmaxf(sqrtf(sq), 1e-12f);
  float z[4] = {v.x * sc, v.y * sc, v.z * sc, v.w * sc};
  *(float4*)&Zout[idx] = make_float4(z[0], z[1], z[2], z[3]);
  unsigned int hi[4];
#pragma unroll
  for (int e = 0; e < 4; ++e) {
    hi[e] = bfr(z[e]);
    T[4 * c4 + e][mloc] = (unsigned short)hi[e];
  }
  *(uint2*)&Zghi[idx] = make_uint2(hi[0] | (hi[1] << 16), hi[2] | (hi[3] << 16));
  __syncthreads();
  const int cloc = t >> 3, m4 = t & 7;
  unsigned int o0 = (unsigned int)T[cloc][4 * m4 + 0] | ((unsigned int)T[cloc][4 * m4 + 1] << 16);
  unsigned int o1 = (unsigned int)T[cloc][4 * m4 + 2] | ((unsigned int)T[cloc][4 * m4 + 3] << 16);
  *(uint2*)&Zthi[(size_t)k * DD * NN + (size_t)cloc * NN + m0 + 4 * m4] = make_uint2(o0, o1);
}

// ---------------- fused MFMA iteration: gram + softmax(k) + aggregate ----------------
// grid (32 n-blocks, NCH chunks) = 512 blocks, 2 blocks/CU (69 KB LDS).
// Double-buffered tiles staged via async global_load_lds (width 16): ONE barrier/step,
// loads for tile st+1 overlap the whole compute of tile st.
template <int NS>
__global__ __launch_bounds__(256, 2) void iter_kernel(const unsigned short* __restrict__ Zghi,
                                                      const unsigned short* __restrict__ Zthi,
                                                      const unsigned int* __restrict__ mbits,
                                                      unsigned int* __restrict__ partU) {
  // [0,8192) buf0 (Zg tile 4096 | Zt tile 4096), [8192,16384) buf1, [16384,..) per-wave P
  __shared__ __align__(16) unsigned int lds[2 * 8192 + 4 * 16 * PSTR];  // 70656 B
  const int t = threadIdx.x;
  const int w = t >> 6;
  const int lane = t & 63;
  const int l15 = lane & 15;
  const int g = lane >> 4;
  const int nw = blockIdx.x * 64 + w * 16;
  const int mchunk = blockIdx.y * (NS * 32);

  const unsigned int* Zg = (const unsigned int*)Zghi;
  const unsigned int* Zt = (const unsigned int*)Zthi;

  // async stage one 32-m tile into buffer b: 8 x 1KB DMA per wave, LDS dst uniform+lane*16
  const int srow = lane >> 2;   // row-in-chunk
  const int sq4 = (lane & 3) * 4;
  auto issue_loads = [&](int b, int mb) {
#pragma unroll
    for (int j = 0; j < 4; ++j) {
      int chunk = 4 * w + j;                 // 16 rows of (k*32+m) linear space
      int row = chunk * 16 + srow;
      int k = row >> 5, rm = row & 31;
      __builtin_amdgcn_global_load_lds(
          (const unsigned int*)&Zg[(size_t)k * (NN * 16) + (size_t)(mb + rm) * 16 + sq4],
          &lds[b * 8192 + chunk * 256], 16, 0, 0);
      __builtin_amdgcn_global_load_lds(
          (const unsigned int*)&Zt[(size_t)k * (NN * 16) + (size_t)rm * (NN / 2) + (mb >> 1) + sq4],
          &lds[b * 8192 + 4096 + chunk * 256], 16, 0, 0);
    }
  };

  // persistent A-frags: A[k] = Zn[n=nw+l15][c=8g..8g+8)
  short8 A[KK];
#pragma unroll
  for (int k = 0; k < KK; ++k)
    A[k] = as_s8(*(const u32x4*)&Zg[(size_t)(k * NN + nw + l15) * 16 + 4 * g]);

  // preload this chunk's mask words (NS x 32-m per n-row)
  unsigned int mwa[4][NS];
#pragma unroll
  for (int r = 0; r < 4; ++r) {
    uint4 m4 = *(const uint4*)&mbits[(size_t)(nw + 4 * g + r) * 64 + (mchunk >> 5)];
    mwa[r][0] = m4.x; mwa[r][1] = m4.y; mwa[r][2] = m4.z; mwa[r][3] = m4.w;
  }

  f32x4 O[KK][2];
#pragma unroll
  for (int k = 0; k < KK; ++k)
#pragma unroll
    for (int ch = 0; ch < 2; ++ch) O[k][ch] = {0.0f, 0.0f, 0.0f, 0.0f};

  issue_loads(0, mchunk);

  unsigned int* Pw = &lds[16384 + w * (16 * PSTR)];

#pragma unroll
  for (int st = 0; st < NS; ++st) {
    __syncthreads();  // single barrier: drains this wave's DMA, syncs buffer st&1
    if (st + 1 < NS) issue_loads((st + 1) & 1, mchunk + (st + 1) * 32);
    const unsigned int* buf = &lds[(st & 1) * 8192];

    // ---- gram + softmax per sub; pack P into registers ----
    unsigned int pp[4][2][4];
#pragma unroll
    for (int sub = 0; sub < 2; ++sub) {
      f32x4 S[KK];
#pragma unroll
      for (int k = 0; k < KK; ++k) {
        int m = 16 * sub + l15;
        u32x4 bh = *(const u32x4*)&buf[(k * 32 + m) * 16 + 4 * g];
        f32x4 z = {0.0f, 0.0f, 0.0f, 0.0f};
        S[k] = MF(A[k], as_s8(bh), z);
      }
#pragma unroll
      for (int r = 0; r < 4; ++r) {
        float e[KK];
        float sum = 0.0f;
#pragma unroll
        for (int k = 0; k < KK; ++k) { e[k] = __expf(S[k][r]); sum += e[k]; }
        int ml = 16 * sub + l15;
        float f = ((mwa[r][st] >> ml) & 1u) ? __builtin_amdgcn_rcpf(sum) : 0.0f;
#pragma unroll
        for (int k = 0; k < KK; ++k) S[k][r] = e[k] * f;
#pragma unroll
        for (int kp = 0; kp < 4; ++kp)
          pp[kp][sub][r] = packp(S[2 * kp][r], S[2 * kp + 1][r]);
      }
    }

    // ---- per k-pair: P write -> read-back (C->A transpose) -> aggregate ----
#pragma unroll
    for (int kp = 0; kp < 4; ++kp) {
#pragma unroll
      for (int sub = 0; sub < 2; ++sub)
#pragma unroll
        for (int r = 0; r < 4; ++r)
          Pw[(4 * g + r) * PSTR + 16 * sub + l15] = pp[kp][sub][r];

      const unsigned int* Pr = &Pw[l15 * PSTR + 8 * g];
      u32x4 a0 = *(const u32x4*)Pr;
      u32x4 a1 = *(const u32x4*)(Pr + 4);
      UU pk0, pk1;
      pk0.u[0] = prm(a0.y, a0.x, SELLO); pk0.u[1] = prm(a0.w, a0.z, SELLO);
      pk0.u[2] = prm(a1.y, a1.x, SELLO); pk0.u[3] = prm(a1.w, a1.z, SELLO);
      pk1.u[0] = prm(a0.y, a0.x, SELHI); pk1.u[1] = prm(a0.w, a0.z, SELHI);
      pk1.u[2] = prm(a1.y, a1.x, SELHI); pk1.u[3] = prm(a1.w, a1.z, SELHI);
#pragma unroll
      for (int kk = 0; kk < 2; ++kk) {
        int k = 2 * kp + kk;
#pragma unroll
        for (int ch = 0; ch < 2; ++ch) {
          int c = 16 * ch + l15;
          u32x4 b = *(const u32x4*)&buf[4096 + (k * 32 + c) * 16 + 4 * g];
          O[k][ch] = MF(kk ? pk1.v : pk0.v, as_s8(b), O[k][ch]);
        }
      }
    }
  }

  // ---- write partials fp16-packed: partU[chunk][k][n][c2] ----
  unsigned int* dst = partU + (size_t)blockIdx.y * ZS2;
  const int even = ((l15 & 1) == 0);
#pragma unroll
  for (int k = 0; k < KK; ++k)
#pragma unroll
    for (int ch = 0; ch < 2; ++ch) {
      f32x4 o = O[k][ch];
#pragma unroll
      for (int r = 0; r < 4; ++r) {
        float partner = __shfl_xor(o[r], 1);
        if (even) {
          dst[(size_t)(k * NN + nw + 4 * g + r) * 16 + ((16 * ch + l15) >> 1)] =
              packh(o[r], partner);
        }
      }
    }
}

// ---------------- final: residual + reduce + l2norm + [N][K*D] output ----------------
template <int NCt>
__global__ __launch_bounds__(256) void ro_kernel(const float* __restrict__ Zin,
                                                 const unsigned int* __restrict__ partU,
                                                 float* __restrict__ out) {
  const int n = blockIdx.x, t = threadIdx.x;
  const int k = t >> 5, c = t & 31;
  float v = Zin[(size_t)(k * NN + n) * DD + c];
#pragma unroll
  for (int j = 0; j < NCt; ++j) {
    unsigned int pu = partU[(size_t)j * ZS2 + (size_t)(k * NN + n) * 16 + (c >> 1)];
    float2 f = unpackh(pu);
    v += (c & 1) ? f.y : f.x;
  }
  float sq = v * v;
#pragma unroll
  for (int off = 16; off > 0; off >>= 1) sq += __shfl_xor(sq, off, 32);
  out[n * (KK * DD) + t] = v / fmaxf(sqrtf(sq), 1e-12f);
}

extern "C" void kernel_launch(void* const* d_in, const int* in_sizes, int n_in,
                              void* d_out, int out_size, void* d_ws, size_t ws_size,
                              hipStream_t stream) {
  const int* adj = (const int*)d_in[0];
  const float* feat = (const float*)d_in[1];
  const float* W = (const float*)d_in[2];
  const float* b = (const float*)d_in[3];
  float* out = (float*)d_out;

  float* Z0 = (float*)d_ws;
  float* Z1 = Z0 + ZSZ;
  unsigned short* Zghi = (unsigned short*)(Z1 + ZSZ);
  unsigned short* Zthi = Zghi + ZSZ;
  unsigned int* mbits = (unsigned int*)(Zthi + ZSZ);
  unsigned int* partU = mbits + NN * 64;  // NCH * 1 MB = 16 MB

  pm_kernel<<<256 + 4096, 256, 0, stream>>>(feat, W, b, Z0, Zghi, Zthi, adj, mbits);

  float* zi = Z0;
  float* zo = Z1;
  for (int it = 0; it < 4; ++it) {
    iter_kernel<4><<<dim3(32, NCH), 256, 0, stream>>>(Zghi, Zthi, mbits, partU);
    if (it < 3) {
      rp_kernel<NCH><<<512, 256, 0, stream>>>(zi, partU, zo, Zghi, Zthi);
      float* tmp = zi; zi = zo; zo = tmp;
    } else {
      ro_kernel<NCH><<<NN, 256, 0, stream>>>(zi, partU, out);
    }
  }
}